// Round 5
// baseline (1552.759 us; speedup 1.0000x reference)
//
#include <hip/hip_runtime.h>
#include <cstdint>
#include <cstddef>

#define TT 512
#define BB 64
#define HH 256
#define NG 1024
#define DI 768
#define KY 32

#define LDP 56   // LDS row pitch (bf16 elems): 112B = 16B-aligned rows, 2-way-only bank aliasing

typedef __attribute__((ext_vector_type(8))) short bfrag_t;
typedef __attribute__((ext_vector_type(4))) float f4_t;

__device__ __forceinline__ float sigf(float x) {
    return __fdividef(1.f, 1.f + __expf(-x));
}
__device__ __forceinline__ float tanhfast(float x) {
    return fmaf(2.f, sigf(2.f * x), -1.f);
}
__device__ __forceinline__ unsigned short bf_hi(float x) {
    return (unsigned short)(__float_as_uint(x) >> 16);        // truncate to bf16
}
__device__ __forceinline__ float bf_hi_f(float x) {
    return __uint_as_float(__float_as_uint(x) & 0xffff0000u); // exact hi part as f32
}

// ---------------------------------------------------------------------------
// kgemm2: G_pre = A @ B^T + bias via split-bf16 MFMA (3 products: hh+hl+lh,
// error ~2^-16 relative — trajectory-safe).  (unchanged)
// ---------------------------------------------------------------------------
__global__ __launch_bounds__(256) void kgemm2(
    const float* __restrict__ sents, const float* __restrict__ Wih,
    const float* __restrict__ bih, const float* __restrict__ bhh,
    float* __restrict__ gpre, int t0)
{
    __shared__ unsigned short Ah[128 * LDP], Al[128 * LDP];
    __shared__ unsigned short Bh[128 * LDP], Bl[128 * LDP];

    const int tid = threadIdx.x;
    const int nb = blockIdx.x;            // N tile 0..7
    const int mb = blockIdx.y;            // M tile
    const int wv = tid >> 6, lane = tid & 63;
    const int wm = (wv >> 1) * 64, wn = (wv & 1) * 64;  // wave quadrant
    const int fl = lane & 15, quad = lane >> 4;

    f4_t acc[4][4];
#pragma unroll
    for (int mi = 0; mi < 4; ++mi)
#pragma unroll
        for (int ni = 0; ni < 4; ++ni) acc[mi][ni] = (f4_t)0.f;

    const int sr = tid >> 1, sk = (tid & 1) * 16;
    const int gr = mb * 128 + sr;                       // global A row
    const float* aptr = sents + ((size_t)(gr & 63) * TT + t0 + (gr >> 6)) * DI + sk;
    const float* bptr = Wih + (size_t)(nb * 128 + sr) * 800 + KY + sk;

    for (int k0 = 0; k0 < DI; k0 += 32) {
        float4 av[4], bv[4];
#pragma unroll
        for (int i = 0; i < 4; ++i) {
            av[i] = *(const float4*)(aptr + k0 + i * 4);
            bv[i] = *(const float4*)(bptr + k0 + i * 4);
        }
        __syncthreads();   // previous compute done reading LDS
#pragma unroll
        for (int i = 0; i < 4; ++i) {
            ushort4 h4, l4;
            h4.x = bf_hi(av[i].x); l4.x = bf_hi(av[i].x - bf_hi_f(av[i].x));
            h4.y = bf_hi(av[i].y); l4.y = bf_hi(av[i].y - bf_hi_f(av[i].y));
            h4.z = bf_hi(av[i].z); l4.z = bf_hi(av[i].z - bf_hi_f(av[i].z));
            h4.w = bf_hi(av[i].w); l4.w = bf_hi(av[i].w - bf_hi_f(av[i].w));
            *(ushort4*)&Ah[sr * LDP + sk + i * 4] = h4;
            *(ushort4*)&Al[sr * LDP + sk + i * 4] = l4;
            h4.x = bf_hi(bv[i].x); l4.x = bf_hi(bv[i].x - bf_hi_f(bv[i].x));
            h4.y = bf_hi(bv[i].y); l4.y = bf_hi(bv[i].y - bf_hi_f(bv[i].y));
            h4.z = bf_hi(bv[i].z); l4.z = bf_hi(bv[i].z - bf_hi_f(bv[i].z));
            h4.w = bf_hi(bv[i].w); l4.w = bf_hi(bv[i].w - bf_hi_f(bv[i].w));
            *(ushort4*)&Bh[sr * LDP + sk + i * 4] = h4;
            *(ushort4*)&Bl[sr * LDP + sk + i * 4] = l4;
        }
        __syncthreads();   // tile staged

        bfrag_t ah[4], al2[4], bh[4], bl2[4];
#pragma unroll
        for (int mi = 0; mi < 4; ++mi) {
            int row = wm + mi * 16 + fl;
            ah[mi]  = *(const bfrag_t*)&Ah[row * LDP + quad * 8];
            al2[mi] = *(const bfrag_t*)&Al[row * LDP + quad * 8];
        }
#pragma unroll
        for (int ni = 0; ni < 4; ++ni) {
            int col = wn + ni * 16 + fl;
            bh[ni]  = *(const bfrag_t*)&Bh[col * LDP + quad * 8];
            bl2[ni] = *(const bfrag_t*)&Bl[col * LDP + quad * 8];
        }
#pragma unroll
        for (int mi = 0; mi < 4; ++mi)
#pragma unroll
            for (int ni = 0; ni < 4; ++ni) {
                acc[mi][ni] = __builtin_amdgcn_mfma_f32_16x16x32_bf16(
                    ah[mi], bh[ni], acc[mi][ni], 0, 0, 0);
                acc[mi][ni] = __builtin_amdgcn_mfma_f32_16x16x32_bf16(
                    ah[mi], bl2[ni], acc[mi][ni], 0, 0, 0);
                acc[mi][ni] = __builtin_amdgcn_mfma_f32_16x16x32_bf16(
                    al2[mi], bh[ni], acc[mi][ni], 0, 0, 0);
            }
    }

    // epilogue: C/D layout col=lane&15, row=quad*4+reg (m89-verified)
#pragma unroll
    for (int ni = 0; ni < 4; ++ni) {
        int gcol = nb * 128 + wn + ni * 16 + fl;
        float bias = bih[gcol] + bhh[gcol];
#pragma unroll
        for (int mi = 0; mi < 4; ++mi) {
            int grow = mb * 128 + wm + mi * 16 + quad * 4;
#pragma unroll
            for (int r = 0; r < 4; ++r)
                gpre[(size_t)(grow + r) * NG + gcol] = acc[mi][ni][r] + bias;
        }
    }
}

// ---------------------------------------------------------------------------
// Kernel S: SHi[tl][b][k] = sents[b][t0+tl][:] @ Waff[k][256:1024]^T + baff[k]
// (unchanged)
// ---------------------------------------------------------------------------
__global__ __launch_bounds__(256) void kshi(
    const float* __restrict__ sents, const float* __restrict__ Waff,
    const float* __restrict__ baff, float* __restrict__ shi, int t0)
{
    const int tid = threadIdx.x;
    const int lane = tid & 63;
    const int r = blockIdx.x * 4 + (tid >> 6);
    const int b = r & 63, tl = r >> 6;
    const float* hi = sents + ((size_t)b * TT + t0 + tl) * DI;
    float p0 = 0.f, p1 = 0.f;
#pragma unroll
    for (int kk = 0; kk < 12; ++kk) {
        int k = kk * 64 + lane;
        float x = hi[k];
        p0 = fmaf(x, Waff[HH + k], p0);
        p1 = fmaf(x, Waff[NG + HH + k], p1);
    }
#pragma unroll
    for (int off = 32; off >= 1; off >>= 1) {
        p0 += __shfl_xor(p0, off, 64);
        p1 += __shfl_xor(p1, off, 64);
    }
    if (lane == 0) {
        shi[(size_t)r * 2 + 0] = p0 + baff[0];
        shi[(size_t)r * 2 + 1] = p1 + baff[1];
    }
}

// ---------------------------------------------------------------------------
// init: zero the packed mailbox words (ws is poisoned 0xAA before every run)
// ---------------------------------------------------------------------------
__global__ void kinit(unsigned long long* __restrict__ hbox) {
    hbox[(size_t)blockIdx.x * 512 + threadIdx.x] = 0ull;
}

// ---------------------------------------------------------------------------
// krec7: krec6 structure, but the Whh slice is pinned in AGPRs via explicit
// v_accvgpr_write/read inline asm.
//   Evidence: R4's asm-opaque pin left VGPR_Count=116 (need ~244) and time
//   unchanged -> compiler spilled wreg to scratch, weight stream persisted.
//   Aggregate check: 256 blk x 256KB/step / 2.05us = 31.2 TB/s ~= 90% of the
//   34.5 TB/s L2 ceiling -> krec IS the L2 roofline on redundant weight
//   re-reads. AGPRs are the only storage the allocator can't silently demote:
//   explicit "a"-class asm is non-rematerializable and needs no memory.
//   128 AGPR + ~116 VGPR fits the 256/thread budget at 2 waves/SIMD.
//   accvgpr_read is volatile so LICM can't hoist 128 copies out of the loop.
// ---------------------------------------------------------------------------
#define WSTASH(dst, src) \
    asm volatile("v_accvgpr_write_b32 %0, %1" : "=a"(dst) : "v"(src))
#define WFMA(acc, gt, kk, c, hcomp) { float _w;                               \
    asm volatile("v_accvgpr_read_b32 %0, %1" : "=v"(_w) : "a"(wag[gt][kk][c]));\
    acc = fmaf(_w, (hcomp), acc); }

__global__ __launch_bounds__(512, 2) void krec7(
    const float* __restrict__ gpre,   // [Tc][64][1024]
    const float* __restrict__ shi,    // [Tc][64][2]
    const float* __restrict__ Whh,    // [1024][256]
    const float* __restrict__ mask,   // [64][512]
    float* __restrict__ out,          // [64][512][2]
    float* __restrict__ sh, float* __restrict__ sc, int* __restrict__ sp,
    unsigned long long* __restrict__ hbox,  // [2][64][4][64]
    const float* __restrict__ Wih, const float* __restrict__ tag,
    const float* __restrict__ Waff,
    int t0, int Tc, int first)
{
    const int blk = blockIdx.x;
    const int g = blk >> 6, b = blk & 63;
    const int tid = threadIdx.x;
    const int w = tid >> 6, lane = tid & 63;
    const int jl = lane & 7, kq = lane >> 3;
    const int jh = w * 8 + jl;
    const int jglob = g * 64 + jh;

    __shared__ float hbl[2][8 * 36];    // blended h state (matvec input)
    __shared__ float hraw[2][8 * 36];   // raw h_new (score input)
    __shared__ float P[2][4][64];
    __shared__ float tg[2][KY];

    // Whh slice -> AGPRs (128 per thread), loaded exactly once.
    float wag[4][8][4];
#pragma unroll
    for (int gt = 0; gt < 4; ++gt) {
        const float4* src = (const float4*)(Whh + (size_t)(gt * HH + jglob) * HH + kq * 32);
#pragma unroll
        for (int kk = 0; kk < 8; ++kk) {
            float4 v = src[kk];
            WSTASH(wag[gt][kk][0], v.x);
            WSTASH(wag[gt][kk][1], v.y);
            WSTASH(wag[gt][kk][2], v.z);
            WSTASH(wag[gt][kk][3], v.w);
        }
    }

    // Waff coeffs for the in-register score: lane owns dims 4*lane..4*lane+3
    const float4 wf0 = *(const float4*)(Waff + 4 * lane);
    const float4 wf1 = *(const float4*)(Waff + NG + 4 * lane);

    if (tid < 2 * KY) tg[tid >> 5][tid & 31] = tag[tid];
    __syncthreads();
    {
        int r = tid >> 8, rem = tid & 255, gt = rem >> 6, j2 = rem & 63;
        int row = gt * HH + g * 64 + j2;
        const float4* wr = (const float4*)(Wih + (size_t)row * 800);
        float s = 0.f;
#pragma unroll
        for (int kk = 0; kk < 8; ++kk) {
            float4 v = wr[kk];
            s = fmaf(v.x, tg[r][kk * 4 + 0], s);
            s = fmaf(v.y, tg[r][kk * 4 + 1], s);
            s = fmaf(v.z, tg[r][kk * 4 + 2], s);
            s = fmaf(v.w, tg[r][kk * 4 + 3], s);
        }
        P[r][gt][j2] = s;
    }

    // gather ownership (fixed per thread across the whole chunk)
    const int gpg = (g + 1 + (tid >> 6)) & 3;   // partner group (valid tid<192)
    const int gj2 = tid & 63;

    float creg, hblreg = 0.f, gblreg = 0.f;
    int pred;
    if (first) {
        creg = 0.f; pred = -1;
        if (tid < 256) hbl[0][(tid >> 5) * 36 + (tid & 31)] = 0.f;
    } else {
        creg = sc[(size_t)b * HH + jglob];
        pred = sp[b];
        if (kq == 0)   hblreg = sh[(size_t)b * HH + jglob];
        if (tid < 192) gblreg = sh[(size_t)b * HH + gpg * 64 + gj2];
        if (tid < 256) hbl[0][(tid >> 5) * 36 + (tid & 31)] = sh[(size_t)b * HH + tid];
    }
    __syncthreads();   // P, hbl[0] ready

    // prefetched step-0 operands
    float cgp0, cgp1, cgp2, cgp3, cmi, cs0, cs1;
    {
        const float* gp = gpre + (size_t)b * NG;
        cgp0 = gp[0 * HH + jglob]; cgp1 = gp[1 * HH + jglob];
        cgp2 = gp[2 * HH + jglob]; cgp3 = gp[3 * HH + jglob];
        cmi = mask[(size_t)b * TT + t0];
        const float* s2 = shi + (size_t)b * 2;
        cs0 = s2[0]; cs1 = s2[1];
    }
    float sc0p = 0.f, sc1p = 0.f;   // shi carry for deferred score

    for (int tl = 0; tl < Tc; ++tl) {
        const int t = t0 + tl;
        const int rp = tl & 1;        // read parity (state h(t))
        const int wp2 = rp ^ 1;       // write parity (state h(t+1))
        const int hp = t & 1;         // mailbox parity

        // ---- deferred score/pred/out for step t-1 (ILP with matvec) ----
        if (tl > 0) {
            float4 hv = *(const float4*)(&hraw[rp][(lane >> 3) * 36 + (lane & 7) * 4]);
            float s0 = hv.x * wf0.x;
            s0 = fmaf(hv.y, wf0.y, s0); s0 = fmaf(hv.z, wf0.z, s0); s0 = fmaf(hv.w, wf0.w, s0);
            float s1 = hv.x * wf1.x;
            s1 = fmaf(hv.y, wf1.y, s1); s1 = fmaf(hv.z, wf1.z, s1); s1 = fmaf(hv.w, wf1.w, s1);
#pragma unroll
            for (int off = 1; off <= 32; off <<= 1) {
                s0 += __shfl_xor(s0, off, 64);
                s1 += __shfl_xor(s1, off, 64);
            }
            float ts0 = s0 + sc0p, ts1 = s1 + sc1p;
            pred = (ts1 > ts0) ? 1 : 0;
            if (g == 0 && tid == 0) {
                float m = fmaxf(ts0, ts1);
                float lse = m + log1pf(expf(-fabsf(ts0 - ts1)));
                float* op = out + ((size_t)b * TT + (t - 1)) * 2;
                op[0] = ts0 - lse; op[1] = ts1 - lse;
            }
        }

        // ---- matvec over blended state (weights read back from AGPRs) ----
        float a0 = 0.f, a1 = 0.f, a2 = 0.f, a3 = 0.f;
        const float4* h4 = (const float4*)(&hbl[rp][kq * 36]);
#pragma unroll
        for (int kk = 0; kk < 8; ++kk) {
            float4 hv = h4[kk];
            WFMA(a0, 0, kk, 0, hv.x); WFMA(a0, 0, kk, 1, hv.y);
            WFMA(a0, 0, kk, 2, hv.z); WFMA(a0, 0, kk, 3, hv.w);
            WFMA(a1, 1, kk, 0, hv.x); WFMA(a1, 1, kk, 1, hv.y);
            WFMA(a1, 1, kk, 2, hv.z); WFMA(a1, 1, kk, 3, hv.w);
            WFMA(a2, 2, kk, 0, hv.x); WFMA(a2, 2, kk, 1, hv.y);
            WFMA(a2, 2, kk, 2, hv.z); WFMA(a2, 2, kk, 3, hv.w);
            WFMA(a3, 3, kk, 0, hv.x); WFMA(a3, 3, kk, 1, hv.y);
            WFMA(a3, 3, kk, 2, hv.z); WFMA(a3, 3, kk, 3, hv.w);
        }
        a0 += __shfl_xor(a0, 8, 64); a0 += __shfl_xor(a0, 16, 64); a0 += __shfl_xor(a0, 32, 64);
        a1 += __shfl_xor(a1, 8, 64); a1 += __shfl_xor(a1, 16, 64); a1 += __shfl_xor(a1, 32, 64);
        a2 += __shfl_xor(a2, 8, 64); a2 += __shfl_xor(a2, 16, 64); a2 += __shfl_xor(a2, 32, 64);
        a3 += __shfl_xor(a3, 8, 64); a3 += __shfl_xor(a3, 16, 64); a3 += __shfl_xor(a3, 32, 64);

        // tag-embedding feedback (pred from the deferred score above)
        float pv0 = 0.f, pv1 = 0.f, pv2 = 0.f, pv3 = 0.f;
        if (pred >= 0) {
            pv0 = P[pred][0][jh]; pv1 = P[pred][1][jh];
            pv2 = P[pred][2][jh]; pv3 = P[pred][3][jh];
        }

        float gi = a0 + cgp0 + pv0;
        float gf = a1 + cgp1 + pv1;
        float gg = a2 + cgp2 + pv2;
        float go = a3 + cgp3 + pv3;
        float ig = sigf(gi), fg = sigf(gf);
        float g2 = tanhfast(gg), og = sigf(go);
        float cn = fmaf(fg, creg, ig * g2);
        float hn = og * tanhfast(cn);
        const float mi = cmi;
        creg = fmaf(cn - creg, mi, creg);   // cn*mi + creg*(1-mi)

        // ---- publish own slice (raw) + stage own raw/blended LDS ----
        if (kq == 0) {
            hblreg = fmaf(hn - hblreg, mi, hblreg);
            const int ji = (jglob >> 5) * 36 + (jglob & 31);
            hraw[wp2][ji] = hn;
            hbl[wp2][ji]  = hblreg;
            unsigned long long wd =
                ((unsigned long long)__float_as_uint(hn) << 32) | (unsigned)(t + 1);
            __hip_atomic_store(&hbox[((size_t)(hp * BB + b) * 4 + g) * 64 + jh], wd,
                               __ATOMIC_RELAXED, __HIP_MEMORY_SCOPE_AGENT);
        }

        // carry shi for the deferred score, then prefetch next-step operands
        sc0p = cs0; sc1p = cs1;
        if (tl + 1 < Tc) {
            const float* gp2 = gpre + ((size_t)(tl + 1) * BB + b) * NG;
            cgp0 = gp2[0 * HH + jglob]; cgp1 = gp2[1 * HH + jglob];
            cgp2 = gp2[2 * HH + jglob]; cgp3 = gp2[3 * HH + jglob];
            cmi = mask[(size_t)b * TT + t + 1];
            const float* s2n = shi + ((size_t)(tl + 1) * BB + b) * 2;
            cs0 = s2n[0]; cs1 = s2n[1];
        }

        // ---- gather partner slices; blend locally with register state ----
        if (tid < 192) {
            const unsigned long long* wpt =
                &hbox[((size_t)(hp * BB + b) * 4 + gpg) * 64 + gj2];
            unsigned long long wv;
            do {
                wv = __hip_atomic_load(wpt, __ATOMIC_RELAXED, __HIP_MEMORY_SCOPE_AGENT);
            } while ((unsigned)wv != (unsigned)(t + 1));
            float raw = __uint_as_float((unsigned)(wv >> 32));
            gblreg = fmaf(raw - gblreg, mi, gblreg);
            const int ji = gpg * 64 + gj2;
            const int jj = (ji >> 5) * 36 + (ji & 31);
            hraw[wp2][jj] = raw;
            hbl[wp2][jj]  = gblreg;
        }
        __syncthreads();   // the ONE barrier: h(t+1) raw+blended complete
    }

    // ---- epilogue: score/pred/out for the chunk's last step ----
    {
        const int rp = Tc & 1;
        float4 hv = *(const float4*)(&hraw[rp][(lane >> 3) * 36 + (lane & 7) * 4]);
        float s0 = hv.x * wf0.x;
        s0 = fmaf(hv.y, wf0.y, s0); s0 = fmaf(hv.z, wf0.z, s0); s0 = fmaf(hv.w, wf0.w, s0);
        float s1 = hv.x * wf1.x;
        s1 = fmaf(hv.y, wf1.y, s1); s1 = fmaf(hv.z, wf1.z, s1); s1 = fmaf(hv.w, wf1.w, s1);
#pragma unroll
        for (int off = 1; off <= 32; off <<= 1) {
            s0 += __shfl_xor(s0, off, 64);
            s1 += __shfl_xor(s1, off, 64);
        }
        float ts0 = s0 + sc0p, ts1 = s1 + sc1p;
        pred = (ts1 > ts0) ? 1 : 0;
        if (g == 0 && tid == 0) {
            float m = fmaxf(ts0, ts1);
            float lse = m + log1pf(expf(-fabsf(ts0 - ts1)));
            float* op = out + ((size_t)b * TT + (t0 + Tc - 1)) * 2;
            op[0] = ts0 - lse; op[1] = ts1 - lse;
        }
    }
    if (kq == 0) {
        sh[(size_t)b * HH + jglob] = hblreg;
        sc[(size_t)b * HH + jglob] = creg;
    }
    if (g == 0 && tid == 0) sp[b] = pred;
}

// ---------------------------------------------------------------------------
extern "C" void kernel_launch(void* const* d_in, const int* in_sizes, int n_in,
                              void* d_out, int out_size, void* d_ws, size_t ws_size,
                              hipStream_t stream) {
    (void)in_sizes; (void)n_in; (void)out_size;
    const float* sents = (const float*)d_in[0];
    const float* mask  = (const float*)d_in[1];
    const float* Wih   = (const float*)d_in[2];
    const float* Whh   = (const float*)d_in[3];
    const float* bih   = (const float*)d_in[4];
    const float* bhh   = (const float*)d_in[5];
    const float* Waff  = (const float*)d_in[6];
    const float* baff  = (const float*)d_in[7];
    const float* tag   = (const float*)d_in[8];
    float* out = (float*)d_out;

    const size_t fixed = (size_t)BB * HH * 4 * 2
                       + BB * 4
                       + (size_t)2 * BB * 4 * 64 * 8
                       + 4096;
    int Tc = 8;
    const int cands[7] = {512, 256, 128, 64, 32, 16, 8};
    for (int i = 0; i < 7; ++i) {
        size_t need = (size_t)cands[i] * BB * NG * 4
                    + (size_t)cands[i] * BB * 2 * 4
                    + fixed;
        if (need <= ws_size) { Tc = cands[i]; break; }
    }

    char* wsp = (char*)d_ws;
    float* gpre = (float*)wsp; wsp += (size_t)Tc * BB * NG * 4;
    float* shiw = (float*)wsp; wsp += (size_t)Tc * BB * 2 * 4;
    float* shst = (float*)wsp; wsp += (size_t)BB * HH * 4;
    float* scst = (float*)wsp; wsp += (size_t)BB * HH * 4;
    int*   spst = (int*)wsp;   wsp += BB * 4;
    unsigned long long* hbox = (unsigned long long*)wsp;

    kinit<<<dim3(64), 512, 0, stream>>>(hbox);

    const int nch = TT / Tc;
    for (int c = 0; c < nch; ++c) {
        const int t0 = c * Tc;
        kgemm2<<<dim3(8, Tc * 64 / 128), 256, 0, stream>>>(sents, Wih, bih, bhh, gpre, t0);
        kshi<<<dim3(Tc * 16), 256, 0, stream>>>(sents, Waff, baff, shiw, t0);
        krec7<<<dim3(256), 512, 0, stream>>>(gpre, shiw, Whh, mask, out,
                                             shst, scst, spst, hbox,
                                             Wih, tag, Waff, t0, Tc, (c == 0) ? 1 : 0);
    }
}

// Round 6
// 1279.575 us; speedup vs baseline: 1.2135x; 1.2135x over previous
//
#include <hip/hip_runtime.h>
#include <cstdint>
#include <cstddef>

#define TT 512
#define BB 64
#define HH 256
#define NG 1024
#define DI 768
#define KY 32

#define LDP 56   // LDS row pitch (bf16 elems) for A tiles: 112B rows, 2-way-only bank aliasing

typedef __attribute__((ext_vector_type(8))) short bfrag_t;
typedef __attribute__((ext_vector_type(4))) float f4_t;

__device__ __forceinline__ float sigf(float x) {
    return __fdividef(1.f, 1.f + __expf(-x));
}
__device__ __forceinline__ float tanhfast(float x) {
    return fmaf(2.f, sigf(2.f * x), -1.f);
}
__device__ __forceinline__ unsigned short bf_hi(float x) {
    return (unsigned short)(__float_as_uint(x) >> 16);        // truncate to bf16
}
__device__ __forceinline__ float bf_hi_f(float x) {
    return __uint_as_float(__float_as_uint(x) & 0xffff0000u); // exact hi part as f32
}

// ---------------------------------------------------------------------------
// kprew: one-time Wih[cols 32:800] -> split-bf16 staging buffers Bsh/Bsl,
// row-major [1024][768], with per-row quad-XOR swizzle so the GEMM can
// global_load_lds into LINEAR LDS and ds_read conflict-free (rule #21:
// inverse-swizzled source + swizzled read, linear dest).
//   physical (row, kst, q, e)  stores  logical k = kst*32 + (q ^ ((row>>1)&3))*8 + e
// ---------------------------------------------------------------------------
__global__ __launch_bounds__(256) void kprew(
    const float* __restrict__ Wih,
    unsigned short* __restrict__ Bsh, unsigned short* __restrict__ Bsl)
{
    const int base = (blockIdx.x * 256 + threadIdx.x) * 4;   // 768 blocks: 786432 elems
    const int row = base / 768;
    const int rem = base % 768;
    const int kst = rem >> 5, q = (rem >> 3) & 3, e0 = rem & 7;
    const int klog = kst * 32 + (q ^ ((row >> 1) & 3)) * 8 + e0;
    const float4 v = *(const float4*)(Wih + (size_t)row * 800 + KY + klog);
    ushort4 h4, l4;
    h4.x = bf_hi(v.x); l4.x = bf_hi(v.x - bf_hi_f(v.x));
    h4.y = bf_hi(v.y); l4.y = bf_hi(v.y - bf_hi_f(v.y));
    h4.z = bf_hi(v.z); l4.z = bf_hi(v.z - bf_hi_f(v.z));
    h4.w = bf_hi(v.w); l4.w = bf_hi(v.w - bf_hi_f(v.w));
    *(ushort4*)&Bsh[base] = h4;
    *(ushort4*)&Bsl[base] = l4;
}

// ---------------------------------------------------------------------------
// kgemm2b: G_pre = A @ B^T + bias via split-bf16 MFMA (3 products hh+hl+lh).
// A-path unchanged (f32 load + in-kernel split into padded LDS).
// B-path NEW: global_load_lds width=16 from pre-converted Bsh/Bsl into linear
// [128][32] LDS; fragment ds_read applies the matching quad-XOR swizzle
// (<=2-way bank aliasing). Removes the 256x-redundant B conversion VALU.
// ---------------------------------------------------------------------------
__global__ __launch_bounds__(256) void kgemm2b(
    const float* __restrict__ sents,
    const unsigned short* __restrict__ Bsh, const unsigned short* __restrict__ Bsl,
    const float* __restrict__ bih, const float* __restrict__ bhh,
    float* __restrict__ gpre, int t0)
{
    __shared__ unsigned short Ah[128 * LDP], Al[128 * LDP];
    __shared__ unsigned short Bh[128 * 32], Bl[128 * 32];   // linear, swizzled content

    const int tid = threadIdx.x;
    const int nb = blockIdx.x;            // N tile 0..7
    const int mb = blockIdx.y;            // M tile
    const int wv = tid >> 6, lane = tid & 63;
    const int wm = (wv >> 1) * 64, wn = (wv & 1) * 64;  // wave quadrant
    const int fl = lane & 15, quad = lane >> 4;

    f4_t acc[4][4];
#pragma unroll
    for (int mi = 0; mi < 4; ++mi)
#pragma unroll
        for (int ni = 0; ni < 4; ++ni) acc[mi][ni] = (f4_t)0.f;

    // A staging role: row sr (0..127), k-offset sk (0 or 16)
    const int sr = tid >> 1, sk = (tid & 1) * 16;
    const int gr = mb * 128 + sr;                       // global A row
    const float* aptr = sents + ((size_t)(gr & 63) * TT + t0 + (gr >> 6)) * DI + sk;

    // B staging role: wave wv stages rows (2*wv+i)*16 + lane/4, 16B chunk lane%4
    const int brow0 = nb * 128 + wv * 32 + (lane >> 2);       // inst i=0
    const unsigned short* bsrc0h = Bsh + (size_t)brow0 * 768 + (lane & 3) * 8;
    const unsigned short* bsrc1h = Bsh + (size_t)(brow0 + 16) * 768 + (lane & 3) * 8;
    const unsigned short* bsrc0l = Bsl + (size_t)brow0 * 768 + (lane & 3) * 8;
    const unsigned short* bsrc1l = Bsl + (size_t)(brow0 + 16) * 768 + (lane & 3) * 8;
    unsigned short* bdst0 = &Bh[(wv * 2 + 0) * 512];          // 1024B per wave-inst
    unsigned short* bdst1 = &Bh[(wv * 2 + 1) * 512];
    unsigned short* bdst0l = &Bl[(wv * 2 + 0) * 512];
    unsigned short* bdst1l = &Bl[(wv * 2 + 1) * 512];

    for (int k0 = 0; k0 < DI; k0 += 32) {
        float4 av[4];
#pragma unroll
        for (int i = 0; i < 4; ++i)
            av[i] = *(const float4*)(aptr + k0 + i * 4);
        __syncthreads();   // previous compute done reading LDS

        // B: async global->LDS (linear dest, pre-swizzled source)
        __builtin_amdgcn_global_load_lds((const void*)(bsrc0h + k0), (void*)bdst0, 16, 0, 0);
        __builtin_amdgcn_global_load_lds((const void*)(bsrc1h + k0), (void*)bdst1, 16, 0, 0);
        __builtin_amdgcn_global_load_lds((const void*)(bsrc0l + k0), (void*)bdst0l, 16, 0, 0);
        __builtin_amdgcn_global_load_lds((const void*)(bsrc1l + k0), (void*)bdst1l, 16, 0, 0);

        // A: split-bf16 into padded LDS
#pragma unroll
        for (int i = 0; i < 4; ++i) {
            ushort4 h4, l4;
            h4.x = bf_hi(av[i].x); l4.x = bf_hi(av[i].x - bf_hi_f(av[i].x));
            h4.y = bf_hi(av[i].y); l4.y = bf_hi(av[i].y - bf_hi_f(av[i].y));
            h4.z = bf_hi(av[i].z); l4.z = bf_hi(av[i].z - bf_hi_f(av[i].z));
            h4.w = bf_hi(av[i].w); l4.w = bf_hi(av[i].w - bf_hi_f(av[i].w));
            *(ushort4*)&Ah[sr * LDP + sk + i * 4] = h4;
            *(ushort4*)&Al[sr * LDP + sk + i * 4] = l4;
        }
        __syncthreads();   // tile staged (compiler drains vmcnt+lgkm before barrier)

        bfrag_t ah[4], al2[4], bh[4], bl2[4];
#pragma unroll
        for (int mi = 0; mi < 4; ++mi) {
            int row = wm + mi * 16 + fl;
            ah[mi]  = *(const bfrag_t*)&Ah[row * LDP + quad * 8];
            al2[mi] = *(const bfrag_t*)&Al[row * LDP + quad * 8];
        }
#pragma unroll
        for (int ni = 0; ni < 4; ++ni) {
            int col = wn + ni * 16 + fl;
            int q2 = quad ^ ((col >> 1) & 3);     // matching read-side swizzle
            bh[ni]  = *(const bfrag_t*)&Bh[col * 32 + q2 * 8];
            bl2[ni] = *(const bfrag_t*)&Bl[col * 32 + q2 * 8];
        }
#pragma unroll
        for (int mi = 0; mi < 4; ++mi)
#pragma unroll
            for (int ni = 0; ni < 4; ++ni) {
                acc[mi][ni] = __builtin_amdgcn_mfma_f32_16x16x32_bf16(
                    ah[mi], bh[ni], acc[mi][ni], 0, 0, 0);
                acc[mi][ni] = __builtin_amdgcn_mfma_f32_16x16x32_bf16(
                    ah[mi], bl2[ni], acc[mi][ni], 0, 0, 0);
                acc[mi][ni] = __builtin_amdgcn_mfma_f32_16x16x32_bf16(
                    al2[mi], bh[ni], acc[mi][ni], 0, 0, 0);
            }
    }

    // epilogue: C/D layout col=lane&15, row=quad*4+reg (m89-verified)
#pragma unroll
    for (int ni = 0; ni < 4; ++ni) {
        int gcol = nb * 128 + wn + ni * 16 + fl;
        float bias = bih[gcol] + bhh[gcol];
#pragma unroll
        for (int mi = 0; mi < 4; ++mi) {
            int grow = mb * 128 + wm + mi * 16 + quad * 4;
#pragma unroll
            for (int r = 0; r < 4; ++r)
                gpre[(size_t)(grow + r) * NG + gcol] = acc[mi][ni][r] + bias;
        }
    }
}

// ---------------------------------------------------------------------------
// Kernel S: SHi[tl][b][k] = sents[b][t0+tl][:] @ Waff[k][256:1024]^T + baff[k]
// (unchanged)
// ---------------------------------------------------------------------------
__global__ __launch_bounds__(256) void kshi(
    const float* __restrict__ sents, const float* __restrict__ Waff,
    const float* __restrict__ baff, float* __restrict__ shi, int t0)
{
    const int tid = threadIdx.x;
    const int lane = tid & 63;
    const int r = blockIdx.x * 4 + (tid >> 6);
    const int b = r & 63, tl = r >> 6;
    const float* hi = sents + ((size_t)b * TT + t0 + tl) * DI;
    float p0 = 0.f, p1 = 0.f;
#pragma unroll
    for (int kk = 0; kk < 12; ++kk) {
        int k = kk * 64 + lane;
        float x = hi[k];
        p0 = fmaf(x, Waff[HH + k], p0);
        p1 = fmaf(x, Waff[NG + HH + k], p1);
    }
#pragma unroll
    for (int off = 32; off >= 1; off >>= 1) {
        p0 += __shfl_xor(p0, off, 64);
        p1 += __shfl_xor(p1, off, 64);
    }
    if (lane == 0) {
        shi[(size_t)r * 2 + 0] = p0 + baff[0];
        shi[(size_t)r * 2 + 1] = p1 + baff[1];
    }
}

// ---------------------------------------------------------------------------
// init: zero the packed mailbox words (ws is poisoned 0xAA before every run)
// ---------------------------------------------------------------------------
__global__ void kinit(unsigned long long* __restrict__ hbox) {
    hbox[(size_t)blockIdx.x * 512 + threadIdx.x] = 0ull;
}

// ---------------------------------------------------------------------------
// krec3 (REVERTED to session-best, 1002us/dispatch, 0 bank conflicts):
// recurrence split 4 ways per batch element; single-RT packed exchange
// (word = f32bits(hn)<<32 | t+1, relaxed agent atomics, parity double-buffer);
// next-step gpre/mask/shi prefetched into registers BEFORE the poll loop.
// ---------------------------------------------------------------------------
__global__ __launch_bounds__(512, 1) void krec3(
    const float* __restrict__ gpre,   // [Tc][64][1024]
    const float* __restrict__ shi,    // [Tc][64][2]
    const float* __restrict__ Whh,    // [1024][256]
    const float* __restrict__ mask,   // [64][512]
    float* __restrict__ out,          // [64][512][2]
    float* __restrict__ sh, float* __restrict__ sc, int* __restrict__ sp,
    unsigned long long* __restrict__ hbox,  // [2][64][4][64]
    const float* __restrict__ Wih, const float* __restrict__ tag,
    const float* __restrict__ Waff,
    int t0, int Tc, int first)
{
    const int blk = blockIdx.x;
    const int g = blk >> 6, b = blk & 63;
    const int tid = threadIdx.x;
    const int w = tid >> 6, lane = tid & 63;
    const int jl = lane & 7, kq = lane >> 3;
    const int jh = w * 8 + jl;
    const int jglob = g * 64 + jh;

    __shared__ float hk[8 * 36];
    __shared__ float hnS[HH];
    __shared__ float P[2][4][64];
    __shared__ float tg[2][KY];
    __shared__ float red[8][2];

    float4 wreg[4][8];
#pragma unroll
    for (int gt = 0; gt < 4; ++gt) {
        const float4* src = (const float4*)(Whh + (size_t)(gt * HH + jglob) * HH + kq * 32);
#pragma unroll
        for (int kk = 0; kk < 8; ++kk) wreg[gt][kk] = src[kk];
    }

    const int sdim = w * 32 + (lane & 31);
    const int stag = lane >> 5;
    const float waffR = Waff[(size_t)stag * NG + sdim];

    if (tid < 2 * KY) tg[tid >> 5][tid & 31] = tag[tid];
    __syncthreads();
    {
        int r = tid >> 8, rem = tid & 255, gt = rem >> 6, j2 = rem & 63;
        int row = gt * HH + g * 64 + j2;
        const float4* wr = (const float4*)(Wih + (size_t)row * 800);
        float s = 0.f;
#pragma unroll
        for (int kk = 0; kk < 8; ++kk) {
            float4 v = wr[kk];
            s = fmaf(v.x, tg[r][kk * 4 + 0], s);
            s = fmaf(v.y, tg[r][kk * 4 + 1], s);
            s = fmaf(v.z, tg[r][kk * 4 + 2], s);
            s = fmaf(v.w, tg[r][kk * 4 + 3], s);
        }
        P[r][gt][j2] = s;
    }

    float creg; int pred;
    if (first) {
        creg = 0.f; pred = -1;
        if (tid < 72) ((float4*)hk)[tid] = make_float4(0.f, 0.f, 0.f, 0.f);
    } else {
        creg = sc[(size_t)b * HH + jglob];
        pred = sp[b];
        if (tid < HH) hk[(tid >> 5) * 36 + (tid & 31)] = sh[(size_t)b * HH + tid];
    }
    __syncthreads();

    // current-step operand registers (prefetched)
    float cgp0, cgp1, cgp2, cgp3, cmi, cs0, cs1;
    {
        const float* gp = gpre + ((size_t)0 * BB + b) * NG;
        cgp0 = gp[0 * HH + jglob]; cgp1 = gp[1 * HH + jglob];
        cgp2 = gp[2 * HH + jglob]; cgp3 = gp[3 * HH + jglob];
        cmi = mask[(size_t)b * TT + t0];
        const float* s2 = shi + ((size_t)0 * BB + b) * 2;
        cs0 = s2[0]; cs1 = s2[1];
    }

    for (int tl = 0; tl < Tc; ++tl) {
        const int t = t0 + tl;
        const int p = t & 1;

        float pv0 = 0.f, pv1 = 0.f, pv2 = 0.f, pv3 = 0.f;
        if (pred >= 0) {
            pv0 = P[pred][0][jh]; pv1 = P[pred][1][jh];
            pv2 = P[pred][2][jh]; pv3 = P[pred][3][jh];
        }

        float a0 = 0.f, a1 = 0.f, a2 = 0.f, a3 = 0.f;
        const float4* h4 = (const float4*)(hk + kq * 36);
#pragma unroll
        for (int kk = 0; kk < 8; ++kk) {
            float4 hv = h4[kk];
            a0 = fmaf(wreg[0][kk].x, hv.x, a0); a0 = fmaf(wreg[0][kk].y, hv.y, a0);
            a0 = fmaf(wreg[0][kk].z, hv.z, a0); a0 = fmaf(wreg[0][kk].w, hv.w, a0);
            a1 = fmaf(wreg[1][kk].x, hv.x, a1); a1 = fmaf(wreg[1][kk].y, hv.y, a1);
            a1 = fmaf(wreg[1][kk].z, hv.z, a1); a1 = fmaf(wreg[1][kk].w, hv.w, a1);
            a2 = fmaf(wreg[2][kk].x, hv.x, a2); a2 = fmaf(wreg[2][kk].y, hv.y, a2);
            a2 = fmaf(wreg[2][kk].z, hv.z, a2); a2 = fmaf(wreg[2][kk].w, hv.w, a2);
            a3 = fmaf(wreg[3][kk].x, hv.x, a3); a3 = fmaf(wreg[3][kk].y, hv.y, a3);
            a3 = fmaf(wreg[3][kk].z, hv.z, a3); a3 = fmaf(wreg[3][kk].w, hv.w, a3);
        }
        a0 += __shfl_xor(a0, 8, 64); a0 += __shfl_xor(a0, 16, 64); a0 += __shfl_xor(a0, 32, 64);
        a1 += __shfl_xor(a1, 8, 64); a1 += __shfl_xor(a1, 16, 64); a1 += __shfl_xor(a1, 32, 64);
        a2 += __shfl_xor(a2, 8, 64); a2 += __shfl_xor(a2, 16, 64); a2 += __shfl_xor(a2, 32, 64);
        a3 += __shfl_xor(a3, 8, 64); a3 += __shfl_xor(a3, 16, 64); a3 += __shfl_xor(a3, 32, 64);

        float gi = a0 + cgp0 + pv0;
        float gf = a1 + cgp1 + pv1;
        float gg = a2 + cgp2 + pv2;
        float go = a3 + cgp3 + pv3;
        float ig = sigf(gi), fg = sigf(gf);
        float g2 = tanhfast(gg), og = sigf(go);
        float cn = fmaf(fg, creg, ig * g2);
        float hn = og * tanhfast(cn);
        float mi = cmi;
        float s2v0 = cs0, s2v1 = cs1;
        creg = cn * mi + creg * (1.f - mi);

        // publish own slice (one packed 8B word per dim, no fence)
        if (kq == 0) {
            unsigned long long wd =
                ((unsigned long long)__float_as_uint(hn) << 32) | (unsigned)(t + 1);
            __hip_atomic_store(&hbox[((size_t)(p * BB + b) * 4 + g) * 64 + jh], wd,
                               __ATOMIC_RELAXED, __HIP_MEMORY_SCOPE_AGENT);
            hnS[jglob] = hn;
        }

        // ---- prefetch next step's operands NOW (hidden under the poll) ----
        if (tl + 1 < Tc) {
            const float* gp2 = gpre + ((size_t)(tl + 1) * BB + b) * NG;
            cgp0 = gp2[0 * HH + jglob]; cgp1 = gp2[1 * HH + jglob];
            cgp2 = gp2[2 * HH + jglob]; cgp3 = gp2[3 * HH + jglob];
            cmi = mask[(size_t)b * TT + t + 1];
            const float* s2n = shi + ((size_t)(tl + 1) * BB + b) * 2;
            cs0 = s2n[0]; cs1 = s2n[1];
        }

        // gather partner slices
        if (tid < 192) {
            int pg = (g + 1 + (tid >> 6)) & 3, j2 = tid & 63;
            const unsigned long long* wp = &hbox[((size_t)(p * BB + b) * 4 + pg) * 64 + j2];
            unsigned long long wv;
            do {
                wv = __hip_atomic_load(wp, __ATOMIC_RELAXED, __HIP_MEMORY_SCOPE_AGENT);
            } while ((unsigned)wv != (unsigned)(t + 1));
            hnS[pg * 64 + j2] = __uint_as_float((unsigned)(wv >> 32));
        }
        __syncthreads();   // B3: hnS complete; hk reads of this step done

        if (tid < HH) {
            int idx = (tid >> 5) * 36 + (tid & 31);
            float hold = hk[idx];
            hk[idx] = hnS[tid] * mi + hold * (1.f - mi);
        }
        float prod = hnS[sdim] * waffR;
        prod += __shfl_xor(prod, 1, 64);
        prod += __shfl_xor(prod, 2, 64);
        prod += __shfl_xor(prod, 4, 64);
        prod += __shfl_xor(prod, 8, 64);
        prod += __shfl_xor(prod, 16, 64);
        if ((lane & 31) == 0) red[w][stag] = prod;
        __syncthreads();   // B4: red + hk complete

        float s0 = red[0][0];
        s0 += red[1][0]; s0 += red[2][0]; s0 += red[3][0];
        s0 += red[4][0]; s0 += red[5][0]; s0 += red[6][0]; s0 += red[7][0];
        float s1 = red[0][1];
        s1 += red[1][1]; s1 += red[2][1]; s1 += red[3][1];
        s1 += red[4][1]; s1 += red[5][1]; s1 += red[6][1]; s1 += red[7][1];
        float ts0 = s0 + s2v0, ts1 = s1 + s2v1;
        pred = (ts1 > ts0) ? 1 : 0;
        if (g == 0 && tid == 0) {
            float m = fmaxf(ts0, ts1);
            float lse = m + log1pf(expf(-fabsf(ts0 - ts1)));
            float* op = out + ((size_t)b * TT + t) * 2;
            op[0] = ts0 - lse; op[1] = ts1 - lse;
        }
    }

    if (kq == 0) {
        sh[(size_t)b * HH + jglob] = hk[(jglob >> 5) * 36 + (jglob & 31)];
        sc[(size_t)b * HH + jglob] = creg;
    }
    if (g == 0 && tid == 0) sp[b] = pred;
}

// ---------------------------------------------------------------------------
extern "C" void kernel_launch(void* const* d_in, const int* in_sizes, int n_in,
                              void* d_out, int out_size, void* d_ws, size_t ws_size,
                              hipStream_t stream) {
    (void)in_sizes; (void)n_in; (void)out_size;
    const float* sents = (const float*)d_in[0];
    const float* mask  = (const float*)d_in[1];
    const float* Wih   = (const float*)d_in[2];
    const float* Whh   = (const float*)d_in[3];
    const float* bih   = (const float*)d_in[4];
    const float* bhh   = (const float*)d_in[5];
    const float* Waff  = (const float*)d_in[6];
    const float* baff  = (const float*)d_in[7];
    const float* tag   = (const float*)d_in[8];
    float* out = (float*)d_out;

    const size_t bsz = (size_t)NG * DI * 2;           // 1.5MB per half
    const size_t fixed = (size_t)BB * HH * 4 * 2
                       + BB * 4
                       + (size_t)2 * BB * 4 * 64 * 8
                       + 2 * bsz
                       + 8192;
    int Tc = 8;
    const int cands[7] = {512, 256, 128, 64, 32, 16, 8};
    for (int i = 0; i < 7; ++i) {
        size_t need = (size_t)cands[i] * BB * NG * 4
                    + (size_t)cands[i] * BB * 2 * 4
                    + fixed;
        if (need <= ws_size) { Tc = cands[i]; break; }
    }

    char* wsp = (char*)d_ws;
    unsigned short* Bsh = (unsigned short*)wsp; wsp += bsz;
    unsigned short* Bsl = (unsigned short*)wsp; wsp += bsz;
    float* gpre = (float*)wsp; wsp += (size_t)Tc * BB * NG * 4;
    float* shiw = (float*)wsp; wsp += (size_t)Tc * BB * 2 * 4;
    float* shst = (float*)wsp; wsp += (size_t)BB * HH * 4;
    float* scst = (float*)wsp; wsp += (size_t)BB * HH * 4;
    int*   spst = (int*)wsp;   wsp += BB * 4;
    unsigned long long* hbox = (unsigned long long*)wsp;

    kinit<<<dim3(64), 512, 0, stream>>>(hbox);
    kprew<<<dim3(768), 256, 0, stream>>>(Wih, Bsh, Bsl);

    const int nch = TT / Tc;
    for (int c = 0; c < nch; ++c) {
        const int t0 = c * Tc;
        kgemm2b<<<dim3(8, Tc * 64 / 128), 256, 0, stream>>>(sents, Bsh, Bsl, bih, bhh, gpre, t0);
        kshi<<<dim3(Tc * 16), 256, 0, stream>>>(sents, Waff, baff, shiw, t0);
        krec3<<<dim3(256), 512, 0, stream>>>(gpre, shiw, Whh, mask, out,
                                             shst, scst, spst, hbox,
                                             Wih, tag, Waff, t0, Tc, (c == 0) ? 1 : 0);
    }
}